// Round 5
// baseline (11344.202 us; speedup 1.0000x reference)
//
#include <hip/hip_runtime.h>
#include <stdint.h>

// Must match numpy float32 rounding exactly: (dx*dx + dy*dy) + dz*dz, no FMA.
#pragma clang fp contract(off)

#define NPT      2048
#define NBATCH   32
#define NPTS     65536
#define MEMBERS  8
#define NTHREADS 512
#define CHUNK    (NPTS / MEMBERS)       // 8192 points per block
#define PPT      (CHUNK / NTHREADS)     // 16 points per thread
#define WPB      (NTHREADS / 64)        // 8 waves per block
#define SLOTS    (MEMBERS * WPB)        // 64 wave-slots per batch

__device__ __forceinline__ uint32_t f2u(float f) { return __float_as_uint(f); }
__device__ __forceinline__ float u2f(uint32_t u) { return __uint_as_float(u); }

// argmax combine: larger value wins; tie -> smaller index (numpy argmax order)
__device__ __forceinline__ void amerge(float& v, int& i, float ov, int oi) {
    if (ov > v || (ov == v && oi < i)) { v = ov; i = oi; }
}

// DPP pairing round (VALU-speed, ~10c vs ~130c for ds_bpermute)
template<int CTRL>
__device__ __forceinline__ void dpp_round(float& v, int& i) {
    float ov = u2f((uint32_t)__builtin_amdgcn_mov_dpp((int)f2u(v), CTRL, 0xf, 0xf, true));
    int   oi = __builtin_amdgcn_mov_dpp(i, CTRL, 0xf, 0xf, true);
    amerge(v, i, ov, oi);
}
__device__ __forceinline__ void swz16_round(float& v, int& i) {   // xor 16
    float ov = u2f((uint32_t)__builtin_amdgcn_ds_swizzle((int)f2u(v), 0x401F));
    int   oi = __builtin_amdgcn_ds_swizzle(i, 0x401F);
    amerge(v, i, ov, oi);
}
__device__ __forceinline__ void shfl32_round(float& v, int& i) {  // xor 32
    float ov = __shfl_xor(v, 32, 64);
    int   oi = __shfl_xor(i, 32, 64);
    amerge(v, i, ov, oi);
}
// full 64-lane argmax: every lane ends with the global (max, min-index)
__device__ __forceinline__ void wave_argmax(float& v, int& i) {
    dpp_round<0xB1>(v, i);    // quad_perm [1,0,3,2] : xor1
    dpp_round<0x4E>(v, i);    // quad_perm [2,3,0,1] : xor2
    dpp_round<0x141>(v, i);   // row_half_mirror     : pairs the 4-groups
    dpp_round<0x140>(v, i);   // row_mirror          : pairs the 8-groups
    swz16_round(v, i);        // xor16
    shfl32_round(v, i);       // xor32
}

__global__ void __launch_bounds__(NTHREADS, 2)
fps_kernel(const float* __restrict__ xyz, int* __restrict__ out,
           uint64_t* __restrict__ cand)
{
    // x in LDS purely as register relief: each thread touches only its own
    // 16 slots (p = tid + k*512) -> no barriers, stride-1 -> conflict-free.
    __shared__ float sx[CHUNK];   // 32 KB

    // Swizzle: a batch's 8 member blocks share blockIdx%8 (XCD heuristic).
    const int i = blockIdx.x;
    const int q = i >> 3;
    const int batch  = (i & 7) * 4 + (q & 3);   // [0,32)
    const int member = q >> 2;                  // [0,8)
    const int tid  = threadIdx.x;
    const int lane = tid & 63;
    const int wv   = tid >> 6;

    const float* xb = xyz + (size_t)batch * 3 * NPTS;
    const int gbase = member * CHUNK;

    float py[PPT], pz[PPT], pd[PPT];    // 48 data floats, arch-VGPR at (512,2)
#pragma unroll
    for (int k = 0; k < PPT; ++k) {
        int p = tid + k * NTHREADS;
        int g = gbase + p;
        sx[p] = xb[g];
        py[k] = xb[NPTS + g];
        pz[k] = xb[2 * NPTS + g];
        pd[k] = 1e10f;
    }

    // First centroid is point 0; first emitted index is 0.
    float cx = xb[0], cy = xb[NPTS], cz = xb[2 * NPTS];
    if (member == 0 && tid == 0) out[(size_t)batch * NPT] = 0;

    // cand[batch][parity][slot]: 64 slots x 8B = 8 lines per (batch,parity).
    uint64_t* cb = cand + (size_t)batch * 2 * SLOTS;
    const int sid = member * WPB + wv;          // this wave's slot [0,64)

    for (int t = 0; t < NPT - 1; ++t) {
        // ---- dist update + per-thread argmax (strict >, ascending k =
        //      ascending global index -> first-occurrence semantics) ----
        float bv = -1.0f;            // all dists >= 0, so always beaten
        int   bi = 0;
#pragma unroll
        for (int k = 0; k < PPT; ++k) {
            int p = tid + k * NTHREADS;
            float dx = sx[p] - cx;
            float dy = py[k] - cy;
            float dz = pz[k] - cz;
            float d  = dx * dx + dy * dy;   // contract(off): mul,mul,add
            d = d + dz * dz;                // then add — matches numpy order
            float nd = fminf(pd[k], d);
            pd[k] = nd;
            bool g = nd > bv;
            bv = g ? nd : bv;
            bi = g ? (gbase + p) : bi;
        }

        // ---- wave argmax (DPP fast path) ----
        wave_argmax(bv, bi);

        // ---- publish this wave's best as one tagged relaxed 64-bit word ----
        // ABA-safe: slot rewritten at t+2 only after its wave passed poll t+1,
        // which requires every wave published t+1, which requires every wave
        // fully read t. Poison (0xAAAA) / stale tags (2046/2045 from previous
        // replay) never match the first polled tags (0/1) -> no memset needed.
        uint64_t* sb = cb + (size_t)(t & 1) * SLOTS;
        const uint32_t tag = (uint32_t)t;
        if (lane == 0) {
            uint64_t w = ((uint64_t)f2u(bv) << 32)
                       | ((uint64_t)(uint32_t)bi << 16) | tag;
            __hip_atomic_store(&sb[sid], w, __ATOMIC_RELAXED,
                               __HIP_MEMORY_SCOPE_AGENT);
        }

        // ---- poll: one slot per lane; masked re-loads until all 64 valid ----
        uint64_t w = 0; bool done = false;
        do {
            if (!done) w = __hip_atomic_load(&sb[lane], __ATOMIC_RELAXED,
                                             __HIP_MEMORY_SCOPE_AGENT);
            done = (uint32_t)(w & 0xFFFFu) == tag;
        } while (!__all(done));

        // ---- global argmax across the 64 slot-candidates ----
        float v  = u2f((uint32_t)(w >> 32));
        int   gi = (int)((w >> 16) & 0xFFFFu);
        wave_argmax(v, gi);

        // new centroid (uniform index; read-only, L1/L2-cached)
        cx = xb[gi];
        cy = xb[NPTS + gi];
        cz = xb[2 * NPTS + gi];
        if (member == 0 && tid == 0) out[(size_t)batch * NPT + t + 1] = gi;
    }
}

extern "C" void kernel_launch(void* const* d_in, const int* in_sizes, int n_in,
                              void* d_out, int out_size, void* d_ws, size_t ws_size,
                              hipStream_t stream)
{
    const float* xyz = (const float*)d_in[0];
    int* out = (int*)d_out;
    uint64_t* cand = (uint64_t*)d_ws;   // 32*2*64*8 = 32 KiB used; no memset needed
    fps_kernel<<<NBATCH * MEMBERS, NTHREADS, 0, stream>>>(xyz, out, cand);
}

// Round 6
// 4301.797 us; speedup vs baseline: 2.6371x; 2.6371x over previous
//
#include <hip/hip_runtime.h>
#include <stdint.h>

// Must match numpy float32 rounding exactly: (dx*dx + dy*dy) + dz*dz, no FMA.
#pragma clang fp contract(off)

#define NPT      2048
#define NBATCH   32
#define NPTS     65536
#define MEMBERS  8
#define NTHREADS 512
#define CHUNK    (NPTS / MEMBERS)       // 8192 points per block
#define PPT      (CHUNK / NTHREADS)     // 16 points per thread
#define WPB      (NTHREADS / 64)        // 8 waves per block
#define PADSLOTS 32                     // 256B per (batch,parity) poll line

__device__ __forceinline__ uint32_t f2u(float f) { return __float_as_uint(f); }
__device__ __forceinline__ float u2f(uint32_t u) { return __uint_as_float(u); }

// argmax combine: larger value wins; tie -> smaller index (numpy argmax order)
__device__ __forceinline__ void amerge(float& v, int& i, float ov, int oi) {
    if (ov > v || (ov == v && oi < i)) { v = ov; i = oi; }
}

// DPP pairing round (VALU-speed ~15c vs ~130c for ds_bpermute)
template<int CTRL>
__device__ __forceinline__ void dpp_round(float& v, int& i) {
    float ov = u2f((uint32_t)__builtin_amdgcn_mov_dpp((int)f2u(v), CTRL, 0xf, 0xf, true));
    int   oi = __builtin_amdgcn_mov_dpp(i, CTRL, 0xf, 0xf, true);
    amerge(v, i, ov, oi);
}
__device__ __forceinline__ void swz16_round(float& v, int& i) {   // lane ^ 16
    float ov = u2f((uint32_t)__builtin_amdgcn_ds_swizzle((int)f2u(v), 0x401F));
    int   oi = __builtin_amdgcn_ds_swizzle(i, 0x401F);
    amerge(v, i, ov, oi);
}
// reduce within each row of 16 lanes (all 16 end with row-best)
__device__ __forceinline__ void row16_argmax(float& v, int& i) {
    dpp_round<0xB1>(v, i);    // quad_perm [1,0,3,2] : xor1
    dpp_round<0x4E>(v, i);    // quad_perm [2,3,0,1] : xor2
    dpp_round<0x141>(v, i);   // row_half_mirror     : merge 4-groups
    dpp_round<0x140>(v, i);   // row_mirror          : merge 8-groups
}
// reduce over 8 candidates replicated as slot (lane&7)
__device__ __forceinline__ void oct_argmax(float& v, int& i) {
    dpp_round<0xB1>(v, i);    // xor1
    dpp_round<0x4E>(v, i);    // xor2
    dpp_round<0x141>(v, i);   // mirror within 8 -> full 8-set
}

__global__ void __launch_bounds__(NTHREADS)
fps_kernel(const float* __restrict__ xyz, int* __restrict__ out,
           uint64_t* __restrict__ cand)
{
    // x in LDS purely as register relief: each thread touches only its own
    // 16 slots (p = tid + k*512) -> no barriers, stride-1 -> conflict-free.
    __shared__ float    sx[CHUNK];          // 32 KB
    __shared__ uint64_t red[WPB * 4];       // 4 row-bests per wave
    __shared__ uint32_t bc[4];              // winner x,y,z (+pad)

    // Swizzle: a batch's 8 member blocks share blockIdx%8 (XCD heuristic;
    // correctness never depends on placement).
    const int i = blockIdx.x;
    const int q = i >> 3;
    const int batch  = (i & 7) * 4 + (q & 3);   // [0,32)
    const int member = q >> 2;                  // [0,8)
    const int tid  = threadIdx.x;
    const int lane = tid & 63;
    const int wv   = tid >> 6;

    const float* xb = xyz + (size_t)batch * 3 * NPTS;
    const int gbase = member * CHUNK;

    float py[PPT], pz[PPT], pd[PPT];    // 48 data floats
#pragma unroll
    for (int k = 0; k < PPT; ++k) {
        int p = tid + k * NTHREADS;
        int g = gbase + p;
        sx[p] = xb[g];
        py[k] = xb[NPTS + g];
        pz[k] = xb[2 * NPTS + g];
        pd[k] = 1e10f;
    }

    // First centroid is point 0; first emitted index is 0.
    float cx = xb[0], cy = xb[NPTS], cz = xb[2 * NPTS];
    if (member == 0 && tid == 0) out[(size_t)batch * NPT] = 0;

    // cand[batch][parity]: 8 live slots inside a padded 256B slab.
    uint64_t* cb = cand + (size_t)batch * 2 * PADSLOTS;

    for (int t = 0; t < NPT - 1; ++t) {
        // ---- dist update + per-thread argmax (strict >, ascending k =
        //      ascending global index -> first-occurrence semantics) ----
        float bv = -1.0f;            // all dists >= 0, so always beaten
        int   bi = 0;
#pragma unroll
        for (int k = 0; k < PPT; ++k) {
            int p = tid + k * NTHREADS;
            float dx = sx[p] - cx;
            float dy = py[k] - cy;
            float dz = pz[k] - cz;
            float d  = dx * dx + dy * dy;   // contract(off): mul,mul,add
            d = d + dz * dz;                // then add — matches numpy order
            float nd = fminf(pd[k], d);
            pd[k] = nd;
            bool g = nd > bv;
            bv = g ? nd : bv;
            bi = g ? (gbase + p) : bi;
        }

        // ---- row-of-16 argmax (4 DPP rounds), one writer per row ----
        row16_argmax(bv, bi);
        if ((lane & 15) == 0)
            red[wv * 4 + (lane >> 4)] = ((uint64_t)f2u(bv) << 32) | (uint32_t)bi;
        __syncthreads();

        if (wv == 0) {
            // ---- cross-wave reduce over the 32 candidates ----
            uint64_t c = red[lane & 31];
            float v  = u2f((uint32_t)(c >> 32));
            int   ix = (int)(uint32_t)(c & 0xFFFFFFFFu);
            row16_argmax(v, ix);     // rows reduce 0..15 / 16..31 (dup'd)
            swz16_round(v, ix);      // merge the two halves -> block best

            // ---- publish block-best as one tagged relaxed 64-bit word ----
            // ABA-safe: a parity slot for t is rewritten at t+2 only after all
            // blocks passed poll t+1, which requires all reads of t done.
            // Poison (0xAAAA) / previous-replay tags (2046/2045) never match
            // the first polled tags (0/1) -> no memset needed.
            uint64_t* sb = cb + (size_t)(t & 1) * PADSLOTS;
            const uint32_t tag = (uint32_t)t;
            if (lane == 0) {
                uint64_t w = ((uint64_t)f2u(v) << 32)
                           | ((uint64_t)(uint32_t)ix << 16) | tag;
                __hip_atomic_store(&sb[member], w, __ATOMIC_RELAXED,
                                   __HIP_MEMORY_SCOPE_AGENT);
            }

            // ---- poll the 8 slots (one line; lane l watches slot l&7) ----
            uint64_t w = 0; bool done = false;
            do {
                if (!done) w = __hip_atomic_load(&sb[lane & 7], __ATOMIC_RELAXED,
                                                 __HIP_MEMORY_SCOPE_AGENT);
                done = (uint32_t)(w & 0xFFFFu) == tag;
            } while (!__all(done));

            // ---- global argmax across the 8 member candidates ----
            float gv = u2f((uint32_t)(w >> 32));
            int   gi = (int)((w >> 16) & 0xFFFFu);
            oct_argmax(gv, gi);

            // winner coords (uniform addr, read-only, cached) + output index
            float wx = xb[gi], wy = xb[NPTS + gi], wz = xb[2 * NPTS + gi];
            if (lane == 0) {
                bc[0] = f2u(wx); bc[1] = f2u(wy); bc[2] = f2u(wz);
                if (member == 0) out[(size_t)batch * NPT + t + 1] = gi;
            }
        }
        __syncthreads();
        cx = u2f(bc[0]); cy = u2f(bc[1]); cz = u2f(bc[2]);
    }
}

extern "C" void kernel_launch(void* const* d_in, const int* in_sizes, int n_in,
                              void* d_out, int out_size, void* d_ws, size_t ws_size,
                              hipStream_t stream)
{
    const float* xyz = (const float*)d_in[0];
    int* out = (int*)d_out;
    uint64_t* cand = (uint64_t*)d_ws;   // 32*2*32*8 = 16 KiB used; no memset needed
    fps_kernel<<<NBATCH * MEMBERS, NTHREADS, 0, stream>>>(xyz, out, cand);
}